// Round 1
// baseline (2413.793 us; speedup 1.0000x reference)
//
#include <hip/hip_runtime.h>

#define N_NODES 100000
#define N_EDGES 1200000
#define DIM 64

// 16 threads per edge; each thread gathers one float4 of the source row and
// atomically accumulates 4 floats into agg[dst]. Lane 0 bumps the edge count.
__global__ __launch_bounds__(256) void scatter_accum(
    const int* __restrict__ src, const int* __restrict__ dst,
    const float* __restrict__ xin, float* __restrict__ agg,
    float* __restrict__ cnt, int nEdges) {
  int t = blockIdx.x * blockDim.x + threadIdx.x;
  int e = t >> 4;
  if (e >= nEdges) return;
  int l = t & 15;
  int s = src[e];
  int d = dst[e];
  float4 v = reinterpret_cast<const float4*>(xin)[(size_t)s * 16 + l];
  float* ap = agg + (size_t)d * DIM + l * 4;
  atomicAdd(ap + 0, v.x);
  atomicAdd(ap + 1, v.y);
  atomicAdd(ap + 2, v.z);
  atomicAdd(ap + 3, v.w);
  if (l == 0) atomicAdd(cnt + d, 1.0f);
}

// One wave per node: out[node][j] = relu(b[j] + sum_k mean[k]*Wn[k][j] + self[k]*Ws[k][j])
// Both 64x64 weights staged in LDS (k-major: W[k*64+j]); lane j owns output dim j.
// sW[k*64+j] reads: 2 lanes/bank (conflict-free per m136); sMean[w][k] is a broadcast.
__global__ __launch_bounds__(256) void sage_linear_relu(
    const float* __restrict__ xin, const float* __restrict__ agg,
    const float* __restrict__ cnt, const float* __restrict__ Wn,
    const float* __restrict__ Ws, const float* __restrict__ bias,
    float* __restrict__ out, int nNodes) {
  __shared__ float sWn[DIM * DIM];
  __shared__ float sWs[DIM * DIM];
  __shared__ float sB[DIM];
  __shared__ float sMean[4][DIM];
  __shared__ float sSelf[4][DIM];

  for (int i = threadIdx.x; i < DIM * DIM / 4; i += blockDim.x) {
    reinterpret_cast<float4*>(sWn)[i] = reinterpret_cast<const float4*>(Wn)[i];
    reinterpret_cast<float4*>(sWs)[i] = reinterpret_cast<const float4*>(Ws)[i];
  }
  if (threadIdx.x < DIM) sB[threadIdx.x] = bias[threadIdx.x];
  __syncthreads();

  int w = threadIdx.x >> 6;     // wave within block (0..3)
  int j = threadIdx.x & 63;     // lane = output dim
  int gw = blockIdx.x * 4 + w;  // global wave id
  int stride = gridDim.x * 4;
  int trips = (nNodes + stride - 1) / stride;  // uniform trip count -> barriers safe

  for (int t = 0; t < trips; ++t) {
    int node = gw + t * stride;
    bool active = node < nNodes;
    if (active) {
      float c = cnt[node];
      float inv = 1.0f / fmaxf(c, 1.0f);
      sMean[w][j] = agg[(size_t)node * DIM + j] * inv;
      sSelf[w][j] = xin[(size_t)node * DIM + j];
    }
    __syncthreads();
    if (active) {
      float acc = sB[j];
#pragma unroll
      for (int k = 0; k < DIM; ++k) {
        acc = fmaf(sMean[w][k], sWn[k * DIM + j], acc);
        acc = fmaf(sSelf[w][k], sWs[k * DIM + j], acc);
      }
      out[(size_t)node * DIM + j] = fmaxf(acc, 0.0f);
    }
    __syncthreads();
  }
}

extern "C" void kernel_launch(void* const* d_in, const int* in_sizes, int n_in,
                              void* d_out, int out_size, void* d_ws, size_t ws_size,
                              hipStream_t stream) {
  const float* x   = (const float*)d_in[0];
  const int*   ei  = (const int*)d_in[1];   // [2, E] int32 per harness contract
  const float* Wn1 = (const float*)d_in[2];
  const float* Ws1 = (const float*)d_in[3];
  const float* b1  = (const float*)d_in[4];
  const float* Wn2 = (const float*)d_in[5];
  const float* Ws2 = (const float*)d_in[6];
  const float* b2  = (const float*)d_in[7];
  const int* src = ei;
  const int* dst = ei + N_EDGES;

  // Workspace layout: agg (N*64 f32) | cnt (N f32) | h1 (N*64 f32)  ~= 51.6 MB
  char* ws = (char*)d_ws;
  float* agg = (float*)ws;
  float* cnt = (float*)(ws + (size_t)N_NODES * DIM * sizeof(float));
  float* h1  = (float*)(ws + (size_t)N_NODES * (DIM + 1) * sizeof(float));
  float* outp = (float*)d_out;

  const int scatterBlocks = (N_EDGES * 16 + 255) / 256;
  const int linBlocks = 1024;  // 4 waves/block; ~25 nodes per wave grid-stride

  // ---- layer 1 ----
  hipMemsetAsync(agg, 0, (size_t)N_NODES * (DIM + 1) * sizeof(float), stream);  // agg+cnt
  scatter_accum<<<scatterBlocks, 256, 0, stream>>>(src, dst, x, agg, cnt, N_EDGES);
  sage_linear_relu<<<linBlocks, 256, 0, stream>>>(x, agg, cnt, Wn1, Ws1, b1, h1, N_NODES);

  // ---- layer 2 ----
  hipMemsetAsync(agg, 0, (size_t)N_NODES * (DIM + 1) * sizeof(float), stream);
  scatter_accum<<<scatterBlocks, 256, 0, stream>>>(src, dst, h1, agg, cnt, N_EDGES);
  sage_linear_relu<<<linBlocks, 256, 0, stream>>>(h1, agg, cnt, Wn2, Ws2, b2, outp, N_NODES);
}

// Round 2
// 795.130 us; speedup vs baseline: 3.0357x; 3.0357x over previous
//
#include <hip/hip_runtime.h>

#define N_NODES 100000
#define N_EDGES 1200000
#define DIM 64
#define SCAN_THREADS 1024

__device__ __forceinline__ float lane_bcast(float v, int k) {
  return __int_as_float(__builtin_amdgcn_readlane(__float_as_int(v), k));
}

// ---- CSR build ------------------------------------------------------------

__global__ __launch_bounds__(256) void hist_deg(
    const int* __restrict__ dst, int* __restrict__ deg, int nEdges) {
  int e = blockIdx.x * blockDim.x + threadIdx.x;
  if (e < nEdges) atomicAdd(&deg[dst[e]], 1);
}

// Single-block exclusive scan of deg[0..n) -> offs[0..n], plus cursor copy.
__global__ __launch_bounds__(SCAN_THREADS) void scan_offs(
    const int* __restrict__ deg, int* __restrict__ offs,
    int* __restrict__ cursor, int n) {
  __shared__ int sums[SCAN_THREADS];
  int tid = threadIdx.x;
  int chunk = (n + SCAN_THREADS - 1) / SCAN_THREADS;
  int start = tid * chunk;
  int end = min(start + chunk, n);
  int s = 0;
  for (int i = start; i < end; ++i) s += deg[i];
  sums[tid] = s;
  __syncthreads();
  // Hillis-Steele inclusive scan over the 1024 chunk sums
  for (int off = 1; off < SCAN_THREADS; off <<= 1) {
    int v = 0;
    if (tid >= off) v = sums[tid - off];
    __syncthreads();
    if (tid >= off) sums[tid] += v;
    __syncthreads();
  }
  int run = (tid == 0) ? 0 : sums[tid - 1];  // exclusive base for this chunk
  for (int i = start; i < end; ++i) {
    offs[i] = run;
    cursor[i] = run;
    run += deg[i];
  }
  if (tid == SCAN_THREADS - 1) offs[n] = sums[SCAN_THREADS - 1];
}

__global__ __launch_bounds__(256) void fill_csr(
    const int* __restrict__ src, const int* __restrict__ dst,
    int* __restrict__ cursor, int* __restrict__ csr_src, int nEdges) {
  int e = blockIdx.x * blockDim.x + threadIdx.x;
  if (e < nEdges) {
    int p = atomicAdd(&cursor[dst[e]], 1);
    csr_src[p] = src[e];
  }
}

// ---- Fused SAGE layer: pull-mean + dual 64x64 matmul + bias + relu --------
// One wave per node. Lane j owns output dim j and holds column j of both
// weight matrices in VGPRs (64+64 regs). Mean/self broadcast via v_readlane
// (k is a compile-time constant after full unroll) -> zero LDS, zero atomics.
__global__ __launch_bounds__(256) void sage_fused(
    const float* __restrict__ xin, const int* __restrict__ offs,
    const int* __restrict__ csr_src, const float* __restrict__ Wn,
    const float* __restrict__ Ws, const float* __restrict__ bias,
    float* __restrict__ out, int nNodes) {
  int j = threadIdx.x & 63;                       // lane = output dim
  int w = threadIdx.x >> 6;                       // wave in block
  int gw = blockIdx.x * 4 + w;                    // global wave id
  int stride = gridDim.x * 4;

  // Stage weight columns into registers (read once per wave lifetime).
  float wn[DIM], wsr[DIM];
#pragma unroll
  for (int k = 0; k < DIM; ++k) {
    wn[k] = Wn[k * DIM + j];
    wsr[k] = Ws[k * DIM + j];
  }
  float bj = bias[j];

  for (int node = gw; node < nNodes; node += stride) {
    int e0 = offs[node];
    int e1 = offs[node + 1];
    // gather-sum neighbor rows: one coalesced 256B read per edge, 4-way ILP
    float a0 = 0.f, a1 = 0.f, a2 = 0.f, a3 = 0.f;
    int e = e0;
    for (; e + 4 <= e1; e += 4) {
      int s0 = csr_src[e + 0];
      int s1 = csr_src[e + 1];
      int s2 = csr_src[e + 2];
      int s3 = csr_src[e + 3];
      a0 += xin[s0 * DIM + j];
      a1 += xin[s1 * DIM + j];
      a2 += xin[s2 * DIM + j];
      a3 += xin[s3 * DIM + j];
    }
    for (; e < e1; ++e) a0 += xin[csr_src[e] * DIM + j];
    float deg = (float)(e1 - e0);
    float inv = 1.0f / fmaxf(deg, 1.0f);
    float mean = ((a0 + a1) + (a2 + a3)) * inv;
    float self = xin[node * DIM + j];

    float acc = bj;
#pragma unroll
    for (int k = 0; k < DIM; ++k) {
      acc = fmaf(lane_bcast(mean, k), wn[k], acc);
      acc = fmaf(lane_bcast(self, k), wsr[k], acc);
    }
    out[node * DIM + j] = fmaxf(acc, 0.0f);
  }
}

extern "C" void kernel_launch(void* const* d_in, const int* in_sizes, int n_in,
                              void* d_out, int out_size, void* d_ws, size_t ws_size,
                              hipStream_t stream) {
  const float* x   = (const float*)d_in[0];
  const int*   ei  = (const int*)d_in[1];   // [2, E] int32
  const float* Wn1 = (const float*)d_in[2];
  const float* Ws1 = (const float*)d_in[3];
  const float* b1  = (const float*)d_in[4];
  const float* Wn2 = (const float*)d_in[5];
  const float* Ws2 = (const float*)d_in[6];
  const float* b2  = (const float*)d_in[7];
  const int* src = ei;
  const int* dst = ei + N_EDGES;

  // ws layout: deg[100k] | offs[100k+1] | cursor[100k] | csr_src[1.2M] | h1[100k*64]
  char* ws = (char*)d_ws;
  int* deg    = (int*)ws;
  int* offs   = (int*)(ws + 1 * 400000 + 0);
  int* cursor = (int*)(ws + 2 * 400000 + 4);
  int* csr    = (int*)(ws + 3 * 400000 + 8);
  float* h1   = (float*)(ws + 3 * 400000 + 8 + (size_t)N_EDGES * 4);
  float* outp = (float*)d_out;

  const int edgeBlocks = (N_EDGES + 255) / 256;
  const int fusedBlocks = 1024;  // 4096 waves, ~25 nodes each (grid-stride)

  // CSR build (reused by both layers)
  hipMemsetAsync(deg, 0, (size_t)N_NODES * sizeof(int), stream);
  hist_deg<<<edgeBlocks, 256, 0, stream>>>(dst, deg, N_EDGES);
  scan_offs<<<1, SCAN_THREADS, 0, stream>>>(deg, offs, cursor, N_NODES);
  fill_csr<<<edgeBlocks, 256, 0, stream>>>(src, dst, cursor, csr, N_EDGES);

  // layer 1: x -> h1 ; layer 2: h1 -> out
  sage_fused<<<fusedBlocks, 256, 0, stream>>>(x, offs, csr, Wn1, Ws1, b1, h1, N_NODES);
  sage_fused<<<fusedBlocks, 256, 0, stream>>>(h1, offs, csr, Wn2, Ws2, b2, outp, N_NODES);
}

// Round 3
// 587.861 us; speedup vs baseline: 4.1061x; 1.3526x over previous
//
#include <hip/hip_runtime.h>

#define N_NODES 100000
#define N_EDGES 1200000
#define DIM 64
#define SCAN_BLOCK 256
#define NB ((N_NODES + SCAN_BLOCK - 1) / SCAN_BLOCK)  // 391

__device__ __forceinline__ float lane_bcast(float v, int k) {
  return __int_as_float(__builtin_amdgcn_readlane(__float_as_int(v), k));
}

// ---- CSR build ------------------------------------------------------------

__global__ __launch_bounds__(256) void hist_deg(
    const int* __restrict__ dst, int* __restrict__ deg, int nEdges) {
  int e = blockIdx.x * blockDim.x + threadIdx.x;
  if (e < nEdges) atomicAdd(&deg[dst[e]], 1);
}

// 1) per-block sums of deg
__global__ __launch_bounds__(SCAN_BLOCK) void block_sums(
    const int* __restrict__ deg, int* __restrict__ bsums, int n) {
  __shared__ int s[SCAN_BLOCK];
  int i = blockIdx.x * SCAN_BLOCK + threadIdx.x;
  s[threadIdx.x] = (i < n) ? deg[i] : 0;
  __syncthreads();
  for (int off = SCAN_BLOCK / 2; off > 0; off >>= 1) {
    if (threadIdx.x < off) s[threadIdx.x] += s[threadIdx.x + off];
    __syncthreads();
  }
  if (threadIdx.x == 0) bsums[blockIdx.x] = s[0];
}

// 2) single-block exclusive scan of the (<=512) block sums
__global__ __launch_bounds__(512) void scan_bsums(int* __restrict__ bsums, int nb) {
  __shared__ int s[512];
  int tid = threadIdx.x;
  s[tid] = (tid < nb) ? bsums[tid] : 0;
  __syncthreads();
  for (int off = 1; off < 512; off <<= 1) {
    int v = (tid >= off) ? s[tid - off] : 0;
    __syncthreads();
    s[tid] += v;
    __syncthreads();
  }
  if (tid < nb) bsums[tid] = (tid == 0) ? 0 : s[tid - 1];  // exclusive base
}

// 3) per-block inclusive scan + block base -> offs/cursor
__global__ __launch_bounds__(SCAN_BLOCK) void scan_final(
    const int* __restrict__ deg, const int* __restrict__ bbase,
    int* __restrict__ offs, int* __restrict__ cursor, int n) {
  __shared__ int s[SCAN_BLOCK];
  int i = blockIdx.x * SCAN_BLOCK + threadIdx.x;
  int v = (i < n) ? deg[i] : 0;
  s[threadIdx.x] = v;
  __syncthreads();
  for (int off = 1; off < SCAN_BLOCK; off <<= 1) {
    int t = (threadIdx.x >= off) ? s[threadIdx.x - off] : 0;
    __syncthreads();
    s[threadIdx.x] += t;
    __syncthreads();
  }
  int base = bbase[blockIdx.x];
  if (i < n) {
    int excl = base + s[threadIdx.x] - v;
    offs[i] = excl;
    cursor[i] = excl;
  }
  if (i == n - 1) offs[n] = base + s[threadIdx.x];
}

__global__ __launch_bounds__(256) void fill_csr(
    const int* __restrict__ src, const int* __restrict__ dst,
    int* __restrict__ cursor, int* __restrict__ csr_src, int nEdges) {
  int e = blockIdx.x * blockDim.x + threadIdx.x;
  if (e < nEdges) {
    int p = atomicAdd(&cursor[dst[e]], 1);
    csr_src[p] = src[e];
  }
}

// ---- Fused SAGE layer: pull-mean + dual 64x64 matmul + bias + relu --------
// One wave per node. Lane j owns output dim j and holds column j of both
// weight matrices in VGPRs. Mean/self broadcast via v_readlane.
__global__ __launch_bounds__(256) void sage_fused(
    const float* __restrict__ xin, const int* __restrict__ offs,
    const int* __restrict__ csr_src, const float* __restrict__ Wn,
    const float* __restrict__ Ws, const float* __restrict__ bias,
    float* __restrict__ out, int nNodes) {
  int j = threadIdx.x & 63;                       // lane = output dim
  int w = threadIdx.x >> 6;                       // wave in block
  int gw = blockIdx.x * 4 + w;                    // global wave id
  int stride = gridDim.x * 4;

  float wn[DIM], wsr[DIM];
#pragma unroll
  for (int k = 0; k < DIM; ++k) {
    wn[k] = Wn[k * DIM + j];
    wsr[k] = Ws[k * DIM + j];
  }
  float bj = bias[j];

  for (int node = gw; node < nNodes; node += stride) {
    int e0 = offs[node];
    int e1 = offs[node + 1];
    float a0 = 0.f, a1 = 0.f, a2 = 0.f, a3 = 0.f;
    int e = e0;
    for (; e + 4 <= e1; e += 4) {
      int s0 = csr_src[e + 0];
      int s1 = csr_src[e + 1];
      int s2 = csr_src[e + 2];
      int s3 = csr_src[e + 3];
      a0 += xin[s0 * DIM + j];
      a1 += xin[s1 * DIM + j];
      a2 += xin[s2 * DIM + j];
      a3 += xin[s3 * DIM + j];
    }
    for (; e < e1; ++e) a0 += xin[csr_src[e] * DIM + j];
    float deg = (float)(e1 - e0);
    float inv = 1.0f / fmaxf(deg, 1.0f);
    float mean = ((a0 + a1) + (a2 + a3)) * inv;
    float self = xin[node * DIM + j];

    float acc = bj;
#pragma unroll
    for (int k = 0; k < DIM; ++k) {
      acc = fmaf(lane_bcast(mean, k), wn[k], acc);
      acc = fmaf(lane_bcast(self, k), wsr[k], acc);
    }
    out[node * DIM + j] = fmaxf(acc, 0.0f);
  }
}

extern "C" void kernel_launch(void* const* d_in, const int* in_sizes, int n_in,
                              void* d_out, int out_size, void* d_ws, size_t ws_size,
                              hipStream_t stream) {
  const float* x   = (const float*)d_in[0];
  const int*   ei  = (const int*)d_in[1];   // [2, E] int32
  const float* Wn1 = (const float*)d_in[2];
  const float* Ws1 = (const float*)d_in[3];
  const float* b1  = (const float*)d_in[4];
  const float* Wn2 = (const float*)d_in[5];
  const float* Ws2 = (const float*)d_in[6];
  const float* b2  = (const float*)d_in[7];
  const int* src = ei;
  const int* dst = ei + N_EDGES;

  // ws layout (ints): deg[N] | offs[N+1] | cursor[N] | bsums[512] | csr[E] | h1[N*64]f
  int* deg    = (int*)d_ws;
  int* offs   = deg + N_NODES;
  int* cursor = offs + N_NODES + 1;
  int* bsums  = cursor + N_NODES;
  int* csr    = bsums + 512;
  float* h1   = (float*)(csr + N_EDGES);
  float* outp = (float*)d_out;

  const int edgeBlocks = (N_EDGES + 255) / 256;
  const int fusedBlocks = 1024;

  // CSR build (reused by both layers)
  hipMemsetAsync(deg, 0, (size_t)N_NODES * sizeof(int), stream);
  hist_deg<<<edgeBlocks, 256, 0, stream>>>(dst, deg, N_EDGES);
  block_sums<<<NB, SCAN_BLOCK, 0, stream>>>(deg, bsums, N_NODES);
  scan_bsums<<<1, 512, 0, stream>>>(bsums, NB);
  scan_final<<<NB, SCAN_BLOCK, 0, stream>>>(deg, bsums, offs, cursor, N_NODES);
  fill_csr<<<edgeBlocks, 256, 0, stream>>>(src, dst, cursor, csr, N_EDGES);

  // layer 1: x -> h1 ; layer 2: h1 -> out
  sage_fused<<<fusedBlocks, 256, 0, stream>>>(x, offs, csr, Wn1, Ws1, b1, h1, N_NODES);
  sage_fused<<<fusedBlocks, 256, 0, stream>>>(h1, offs, csr, Wn2, Ws2, b2, outp, N_NODES);
}

// Round 4
// 547.541 us; speedup vs baseline: 4.4084x; 1.0736x over previous
//
#include <hip/hip_runtime.h>

#define N_NODES 100000
#define N_EDGES 1200000
#define DIM 64
#define SCAN_BLOCK 256
#define NB ((N_NODES + SCAN_BLOCK - 1) / SCAN_BLOCK)  // 391

__device__ __forceinline__ float lane_bcast(float v, int k) {
  return __int_as_float(__builtin_amdgcn_readlane(__float_as_int(v), k));
}

// ---- CSR build ------------------------------------------------------------

__global__ __launch_bounds__(256) void hist_deg(
    const int* __restrict__ dst, int* __restrict__ deg, int nEdges) {
  int e = blockIdx.x * blockDim.x + threadIdx.x;
  if (e < nEdges) atomicAdd(&deg[dst[e]], 1);
}

__global__ __launch_bounds__(SCAN_BLOCK) void block_sums(
    const int* __restrict__ deg, int* __restrict__ bsums, int n) {
  __shared__ int s[SCAN_BLOCK];
  int i = blockIdx.x * SCAN_BLOCK + threadIdx.x;
  s[threadIdx.x] = (i < n) ? deg[i] : 0;
  __syncthreads();
  for (int off = SCAN_BLOCK / 2; off > 0; off >>= 1) {
    if (threadIdx.x < off) s[threadIdx.x] += s[threadIdx.x + off];
    __syncthreads();
  }
  if (threadIdx.x == 0) bsums[blockIdx.x] = s[0];
}

__global__ __launch_bounds__(512) void scan_bsums(int* __restrict__ bsums, int nb) {
  __shared__ int s[512];
  int tid = threadIdx.x;
  s[tid] = (tid < nb) ? bsums[tid] : 0;
  __syncthreads();
  for (int off = 1; off < 512; off <<= 1) {
    int v = (tid >= off) ? s[tid - off] : 0;
    __syncthreads();
    s[tid] += v;
    __syncthreads();
  }
  if (tid < nb) bsums[tid] = (tid == 0) ? 0 : s[tid - 1];  // exclusive base
}

__global__ __launch_bounds__(SCAN_BLOCK) void scan_final(
    const int* __restrict__ deg, const int* __restrict__ bbase,
    int* __restrict__ offs, int* __restrict__ cursor, int n) {
  __shared__ int s[SCAN_BLOCK];
  int i = blockIdx.x * SCAN_BLOCK + threadIdx.x;
  int v = (i < n) ? deg[i] : 0;
  s[threadIdx.x] = v;
  __syncthreads();
  for (int off = 1; off < SCAN_BLOCK; off <<= 1) {
    int t = (threadIdx.x >= off) ? s[threadIdx.x - off] : 0;
    __syncthreads();
    s[threadIdx.x] += t;
    __syncthreads();
  }
  int base = bbase[blockIdx.x];
  if (i < n) {
    int excl = base + s[threadIdx.x] - v;
    offs[i] = excl;
    cursor[i] = excl;
  }
  if (i == n - 1) offs[n] = base + s[threadIdx.x];
}

__global__ __launch_bounds__(256) void fill_csr(
    const int* __restrict__ src, const int* __restrict__ dst,
    int* __restrict__ cursor, int* __restrict__ csr_src, int nEdges) {
  int e = blockIdx.x * blockDim.x + threadIdx.x;
  if (e < nEdges) {
    int p = atomicAdd(&cursor[dst[e]], 1);
    csr_src[p] = src[e];
  }
}

// ---- Fused SAGE layer -----------------------------------------------------
// One wave per ~32 nodes (grid-stride, all waves resident). Lane j owns output
// dim j; columns j of Wn/Ws are PINNED in VGPRs via empty-asm (the round-3
// compiler rematerialized them per node -> 32KB/node L1 refetch; VGPR_Count
// was 76 instead of ~160). launch_bounds(256,3): cap 170 VGPR, 3 waves/SIMD.
__global__ __launch_bounds__(256, 3) void sage_fused(
    const float* __restrict__ xin, const int* __restrict__ offs,
    const int* __restrict__ csr_src, const float* __restrict__ Wn,
    const float* __restrict__ Ws, const float* __restrict__ bias,
    float* __restrict__ out, int nNodes) {
  int j = threadIdx.x & 63;
  int w = threadIdx.x >> 6;
  int gw = blockIdx.x * 4 + w;
  int stride = gridDim.x * 4;

  float wn[DIM], wsr[DIM];
#pragma unroll
  for (int k = 0; k < DIM; ++k) {
    wn[k] = Wn[k * DIM + j];
    asm volatile("" : "+v"(wn[k]));   // pin in VGPR; block rematerialization
  }
#pragma unroll
  for (int k = 0; k < DIM; ++k) {
    wsr[k] = Ws[k * DIM + j];
    asm volatile("" : "+v"(wsr[k]));
  }
  float bj = bias[j];

  for (int node = gw; node < nNodes; node += stride) {
    int e0 = offs[node];
    int e1 = offs[node + 1];
    // gather-sum neighbor rows: 8 outstanding coalesced 256B reads
    float a0 = 0.f, a1 = 0.f, a2 = 0.f, a3 = 0.f;
    int e = e0;
    for (; e + 8 <= e1; e += 8) {
      int s0 = csr_src[e + 0], s1 = csr_src[e + 1];
      int s2 = csr_src[e + 2], s3 = csr_src[e + 3];
      int s4 = csr_src[e + 4], s5 = csr_src[e + 5];
      int s6 = csr_src[e + 6], s7 = csr_src[e + 7];
      float v0 = xin[s0 * DIM + j], v1 = xin[s1 * DIM + j];
      float v2 = xin[s2 * DIM + j], v3 = xin[s3 * DIM + j];
      float v4 = xin[s4 * DIM + j], v5 = xin[s5 * DIM + j];
      float v6 = xin[s6 * DIM + j], v7 = xin[s7 * DIM + j];
      a0 += v0 + v4;
      a1 += v1 + v5;
      a2 += v2 + v6;
      a3 += v3 + v7;
    }
    for (; e < e1; ++e) a0 += xin[csr_src[e] * DIM + j];
    float deg = (float)(e1 - e0);
    float inv = 1.0f / fmaxf(deg, 1.0f);
    float mean = ((a0 + a1) + (a2 + a3)) * inv;
    float self = xin[node * DIM + j];

    // dual matvec: separate accumulator chains for neigh/self
    float accn = bj, accs = 0.f;
#pragma unroll
    for (int k = 0; k < DIM; ++k) {
      accn = fmaf(lane_bcast(mean, k), wn[k], accn);
      accs = fmaf(lane_bcast(self, k), wsr[k], accs);
    }
    out[node * DIM + j] = fmaxf(accn + accs, 0.0f);
  }
}

extern "C" void kernel_launch(void* const* d_in, const int* in_sizes, int n_in,
                              void* d_out, int out_size, void* d_ws, size_t ws_size,
                              hipStream_t stream) {
  const float* x   = (const float*)d_in[0];
  const int*   ei  = (const int*)d_in[1];
  const float* Wn1 = (const float*)d_in[2];
  const float* Ws1 = (const float*)d_in[3];
  const float* b1  = (const float*)d_in[4];
  const float* Wn2 = (const float*)d_in[5];
  const float* Ws2 = (const float*)d_in[6];
  const float* b2  = (const float*)d_in[7];
  const int* src = ei;
  const int* dst = ei + N_EDGES;

  // ws layout (ints): deg[N] | offs[N+1] | cursor[N] | bsums[512] | csr[E] | h1[N*64]f
  int* deg    = (int*)d_ws;
  int* offs   = deg + N_NODES;
  int* cursor = offs + N_NODES + 1;
  int* bsums  = cursor + N_NODES;
  int* csr    = bsums + 512;
  float* h1   = (float*)(csr + N_EDGES);
  float* outp = (float*)d_out;

  const int edgeBlocks = (N_EDGES + 255) / 256;
  const int fusedBlocks = 768;  // 3 blocks/CU @ 3 waves/SIMD -> all resident

  hipMemsetAsync(deg, 0, (size_t)N_NODES * sizeof(int), stream);
  hist_deg<<<edgeBlocks, 256, 0, stream>>>(dst, deg, N_EDGES);
  block_sums<<<NB, SCAN_BLOCK, 0, stream>>>(deg, bsums, N_NODES);
  scan_bsums<<<1, 512, 0, stream>>>(bsums, NB);
  scan_final<<<NB, SCAN_BLOCK, 0, stream>>>(deg, bsums, offs, cursor, N_NODES);
  fill_csr<<<edgeBlocks, 256, 0, stream>>>(src, dst, cursor, csr, N_EDGES);

  sage_fused<<<fusedBlocks, 256, 0, stream>>>(x, offs, csr, Wn1, Ws1, b1, h1, N_NODES);
  sage_fused<<<fusedBlocks, 256, 0, stream>>>(h1, offs, csr, Wn2, Ws2, b2, outp, N_NODES);
}

// Round 5
// 540.743 us; speedup vs baseline: 4.4638x; 1.0126x over previous
//
#include <hip/hip_runtime.h>

#define N_NODES 100000
#define N_EDGES 1200000
#define DIM 64
#define SCAN_BLOCK 256
#define NB ((N_NODES + SCAN_BLOCK - 1) / SCAN_BLOCK)  // 391

__device__ __forceinline__ float lane_bcast(float v, int k) {
  return __int_as_float(__builtin_amdgcn_readlane(__float_as_int(v), k));
}

// ---- CSR build ------------------------------------------------------------

__global__ __launch_bounds__(256) void hist_deg(
    const int* __restrict__ dst, int* __restrict__ deg, int nEdges) {
  int e = blockIdx.x * blockDim.x + threadIdx.x;
  if (e < nEdges) atomicAdd(&deg[dst[e]], 1);
}

__global__ __launch_bounds__(SCAN_BLOCK) void block_sums(
    const int* __restrict__ deg, int* __restrict__ bsums, int n) {
  __shared__ int s[SCAN_BLOCK];
  int i = blockIdx.x * SCAN_BLOCK + threadIdx.x;
  s[threadIdx.x] = (i < n) ? deg[i] : 0;
  __syncthreads();
  for (int off = SCAN_BLOCK / 2; off > 0; off >>= 1) {
    if (threadIdx.x < off) s[threadIdx.x] += s[threadIdx.x + off];
    __syncthreads();
  }
  if (threadIdx.x == 0) bsums[blockIdx.x] = s[0];
}

__global__ __launch_bounds__(512) void scan_bsums(int* __restrict__ bsums, int nb) {
  __shared__ int s[512];
  int tid = threadIdx.x;
  s[tid] = (tid < nb) ? bsums[tid] : 0;
  __syncthreads();
  for (int off = 1; off < 512; off <<= 1) {
    int v = (tid >= off) ? s[tid - off] : 0;
    __syncthreads();
    s[tid] += v;
    __syncthreads();
  }
  if (tid < nb) bsums[tid] = (tid == 0) ? 0 : s[tid - 1];  // exclusive base
}

__global__ __launch_bounds__(SCAN_BLOCK) void scan_final(
    const int* __restrict__ deg, const int* __restrict__ bbase,
    int* __restrict__ offs, int* __restrict__ cursor, int n) {
  __shared__ int s[SCAN_BLOCK];
  int i = blockIdx.x * SCAN_BLOCK + threadIdx.x;
  int v = (i < n) ? deg[i] : 0;
  s[threadIdx.x] = v;
  __syncthreads();
  for (int off = 1; off < SCAN_BLOCK; off <<= 1) {
    int t = (threadIdx.x >= off) ? s[threadIdx.x - off] : 0;
    __syncthreads();
    s[threadIdx.x] += t;
    __syncthreads();
  }
  int base = bbase[blockIdx.x];
  if (i < n) {
    int excl = base + s[threadIdx.x] - v;
    offs[i] = excl;
    cursor[i] = excl;
  }
  if (i == n - 1) offs[n] = base + s[threadIdx.x];
}

__global__ __launch_bounds__(256) void fill_csr(
    const int* __restrict__ src, const int* __restrict__ dst,
    int* __restrict__ cursor, int* __restrict__ csr_src, int nEdges) {
  int e = blockIdx.x * blockDim.x + threadIdx.x;
  if (e < nEdges) {
    int p = atomicAdd(&cursor[dst[e]], 1);
    csr_src[p] = src[e];
  }
}

// ---- Fused SAGE layer v3 --------------------------------------------------
// Weights in LDS (32 KB/block; sW[k*64+j] -> 2 lanes/bank = conflict-free).
// Each wave processes TWO nodes per iteration so the 2 weight ds_reads per k
// are amortized over 4 fma + 4 readlane (VALU-bound, not LDS-issue-bound).
// Round-4 lesson: 128-float register arrays get spilled (VGPR_Count=80),
// re-reading 512 B/thread/node through L1 -> ~80 us/layer. LDS is the home.
__global__ __launch_bounds__(256) void sage_fused(
    const float* __restrict__ xin, const int* __restrict__ offs,
    const int* __restrict__ csr_src, const float* __restrict__ Wn,
    const float* __restrict__ Ws, const float* __restrict__ bias,
    float* __restrict__ out, int nNodes) {
  __shared__ float sWn[DIM * DIM];
  __shared__ float sWs[DIM * DIM];
  for (int i = threadIdx.x; i < DIM * DIM / 4; i += 256) {
    reinterpret_cast<float4*>(sWn)[i] = reinterpret_cast<const float4*>(Wn)[i];
    reinterpret_cast<float4*>(sWs)[i] = reinterpret_cast<const float4*>(Ws)[i];
  }
  __syncthreads();

  int j = threadIdx.x & 63;
  int w = threadIdx.x >> 6;
  float bj = bias[j];
  int gw = blockIdx.x * 4 + w;
  int nw = gridDim.x * 4;

  // N_NODES is even: node pair (2p, 2p+1) always fully valid.
  for (int p = gw; 2 * p < nNodes; p += nw) {
    int n0 = 2 * p, n1 = 2 * p + 1;

    float mean0, self0, mean1, self1;
    // gather node n0 (8-deep ILP)
    {
      int e0 = offs[n0], e1 = offs[n0 + 1];
      float a0 = 0, a1 = 0, a2 = 0, a3 = 0, a4 = 0, a5 = 0, a6 = 0, a7 = 0;
      int e = e0;
      for (; e + 8 <= e1; e += 8) {
        int s0 = csr_src[e + 0], s1 = csr_src[e + 1];
        int s2 = csr_src[e + 2], s3 = csr_src[e + 3];
        int s4 = csr_src[e + 4], s5 = csr_src[e + 5];
        int s6 = csr_src[e + 6], s7 = csr_src[e + 7];
        a0 += xin[s0 * DIM + j]; a1 += xin[s1 * DIM + j];
        a2 += xin[s2 * DIM + j]; a3 += xin[s3 * DIM + j];
        a4 += xin[s4 * DIM + j]; a5 += xin[s5 * DIM + j];
        a6 += xin[s6 * DIM + j]; a7 += xin[s7 * DIM + j];
      }
      for (; e < e1; ++e) a0 += xin[csr_src[e] * DIM + j];
      float sum = ((a0 + a1) + (a2 + a3)) + ((a4 + a5) + (a6 + a7));
      mean0 = sum * (1.0f / fmaxf((float)(e1 - e0), 1.0f));
      self0 = xin[n0 * DIM + j];
    }
    // gather node n1
    {
      int e0 = offs[n1], e1 = offs[n1 + 1];
      float a0 = 0, a1 = 0, a2 = 0, a3 = 0, a4 = 0, a5 = 0, a6 = 0, a7 = 0;
      int e = e0;
      for (; e + 8 <= e1; e += 8) {
        int s0 = csr_src[e + 0], s1 = csr_src[e + 1];
        int s2 = csr_src[e + 2], s3 = csr_src[e + 3];
        int s4 = csr_src[e + 4], s5 = csr_src[e + 5];
        int s6 = csr_src[e + 6], s7 = csr_src[e + 7];
        a0 += xin[s0 * DIM + j]; a1 += xin[s1 * DIM + j];
        a2 += xin[s2 * DIM + j]; a3 += xin[s3 * DIM + j];
        a4 += xin[s4 * DIM + j]; a5 += xin[s5 * DIM + j];
        a6 += xin[s6 * DIM + j]; a7 += xin[s7 * DIM + j];
      }
      for (; e < e1; ++e) a0 += xin[csr_src[e] * DIM + j];
      float sum = ((a0 + a1) + (a2 + a3)) + ((a4 + a5) + (a6 + a7));
      mean1 = sum * (1.0f / fmaxf((float)(e1 - e0), 1.0f));
      self1 = xin[n1 * DIM + j];
    }

    // dual-node matvec: weight reads shared, 4 independent acc chains
    float a0n = bj, a0s = 0.f, a1n = bj, a1s = 0.f;
#pragma unroll
    for (int k = 0; k < DIM; ++k) {
      float wnk = sWn[k * DIM + j];
      float wsk = sWs[k * DIM + j];
      a0n = fmaf(lane_bcast(mean0, k), wnk, a0n);
      a0s = fmaf(lane_bcast(self0, k), wsk, a0s);
      a1n = fmaf(lane_bcast(mean1, k), wnk, a1n);
      a1s = fmaf(lane_bcast(self1, k), wsk, a1s);
    }
    out[n0 * DIM + j] = fmaxf(a0n + a0s, 0.0f);
    out[n1 * DIM + j] = fmaxf(a1n + a1s, 0.0f);
  }
}

extern "C" void kernel_launch(void* const* d_in, const int* in_sizes, int n_in,
                              void* d_out, int out_size, void* d_ws, size_t ws_size,
                              hipStream_t stream) {
  const float* x   = (const float*)d_in[0];
  const int*   ei  = (const int*)d_in[1];
  const float* Wn1 = (const float*)d_in[2];
  const float* Ws1 = (const float*)d_in[3];
  const float* b1  = (const float*)d_in[4];
  const float* Wn2 = (const float*)d_in[5];
  const float* Ws2 = (const float*)d_in[6];
  const float* b2  = (const float*)d_in[7];
  const int* src = ei;
  const int* dst = ei + N_EDGES;

  // ws layout (ints): deg[N] | offs[N+1] | cursor[N] | bsums[512] | csr[E] | h1[N*64]f
  int* deg    = (int*)d_ws;
  int* offs   = deg + N_NODES;
  int* cursor = offs + N_NODES + 1;
  int* bsums  = cursor + N_NODES;
  int* csr    = bsums + 512;
  float* h1   = (float*)(csr + N_EDGES);
  float* outp = (float*)d_out;

  const int edgeBlocks = (N_EDGES + 255) / 256;
  const int fusedBlocks = 1280;  // 5 blocks/CU (LDS-bound occupancy), 2 nodes/wave/iter

  hipMemsetAsync(deg, 0, (size_t)N_NODES * sizeof(int), stream);
  hist_deg<<<edgeBlocks, 256, 0, stream>>>(dst, deg, N_EDGES);
  block_sums<<<NB, SCAN_BLOCK, 0, stream>>>(deg, bsums, N_NODES);
  scan_bsums<<<1, 512, 0, stream>>>(bsums, NB);
  scan_final<<<NB, SCAN_BLOCK, 0, stream>>>(deg, bsums, offs, cursor, N_NODES);
  fill_csr<<<edgeBlocks, 256, 0, stream>>>(src, dst, cursor, csr, N_EDGES);

  sage_fused<<<fusedBlocks, 256, 0, stream>>>(x, offs, csr, Wn1, Ws1, b1, h1, N_NODES);
  sage_fused<<<fusedBlocks, 256, 0, stream>>>(h1, offs, csr, Wn2, Ws2, b2, outp, N_NODES);
}